// Round 7
// baseline (18.912 us; speedup 1.0000x reference)
//
#include <hip/hip_runtime.h>
#include <hip/hip_bf16.h>

typedef __attribute__((ext_vector_type(8))) short bf16x8;   // MFMA A/B frag (8 bf16)
typedef __attribute__((ext_vector_type(4))) float f32x4;    // MFMA C/D frag
typedef __attribute__((ext_vector_type(4))) unsigned int u32x4;

constexpr int BM = 32;      // output rows (h) per block
constexpr int BN = 32;      // output cols (w) per block
constexpr int BK = 32;      // points per K-step
constexpr int NPTS = 4096;
constexpr int HH = 256;
constexpr int WW = 256;
constexpr int SEGCAP = 128;             // per-wave staging capacity (mean ~40)
constexpr int CCAP = 4 * SEGCAP + BK;   // compacted + tail pad

// S = sqrt(INV_VAR * log2(e)); exp(-INV_VAR*d^2) = exp2(-(S*d)^2)
#define SCALE_S 0.56621453f
// cutoff: dropped-point contribution <= 1e5*2^-32 = 2.3e-5 each
#define DCUT 10.0f

// HW packed f32->bf16 (RNE), D.lo = bf16(lo), D.hi = bf16(hi)
__device__ inline unsigned cvtpk(float lo, float hi) {
    unsigned r;
    asm("v_cvt_pk_bf16_f32 %0, %1, %2" : "=v"(r) : "v"(lo), "v"(hi));
    return r;
}

// 4 waves/block, each wave owns one 16x16 output quadrant.
// 2048 blocks -> 8 blocks/CU.  Main loop: no barriers, no global loads.
__global__ __launch_bounds__(256, 8) void soft_raster_kernel(
    const float* __restrict__ p2d,   // (32, 4096, 2)
    const float* __restrict__ pz,    // (32, 4096)
    float* __restrict__ out)         // (32, 256, 256)
{
    const int bk  = blockIdx.z;
    const int tm  = blockIdx.y * BM;
    const int tn  = blockIdx.x * BN;
    const int tid = threadIdx.x;

    __shared__ float sxs[4 * SEGCAP], sys[4 * SEGCAP], szi[4 * SEGCAP];
    __shared__ __align__(16) float cxs[CCAP], cys[CCAP], czi[CCAP];
    __shared__ int scnt[4];

    const int wid  = tid >> 6;          // wave 0..3 -> 2x2 quadrants
    const int lane = tid & 63;
    const int wm   = (wid >> 1) << 4;   // wave row offset (0/16)
    const int wn   = (wid & 1) << 4;    // wave col offset (0/16)
    const int g    = lane >> 4;         // k-group 0..3
    const int r    = lane & 15;

    const size_t pbase = (size_t)bk * NPTS;
    const float2* __restrict__ pxy = reinterpret_cast<const float2*>(p2d) + pbase;

    const float xlo = (float)tn - DCUT, xhi = (float)(tn + BN - 1) + DCUT;
    const float ylo = (float)tm - DCUT, yhi = (float)(tm + BM - 1) + DCUT;

    // ---- single-pass scan: stage pre-scaled VALUES into per-wave segments ----
    // wave w owns k in [w*1024, (w+1)*1024), writes segment [w*128 ...)
    int base = 0;
    #pragma unroll 4
    for (int it = 0; it < 16; ++it) {
        const int k = (wid << 10) + (it << 6) + lane;
        float2 xy = pxy[k];
        bool in = (xy.x > xlo) && (xy.x < xhi) && (xy.y > ylo) && (xy.y < yhi);
        unsigned long long b = __ballot(in);
        int pos = __popcll(b & ((1ull << lane) - 1ull));
        const int o = base + pos;
        if (in && o < SEGCAP) {
            const int s = (wid << 7) + o;
            sxs[s] = xy.x * SCALE_S;
            sys[s] = xy.y * SCALE_S;
            szi[s] = -__builtin_amdgcn_logf(fmaxf(pz[pbase + k], 1e-5f));
        }
        base += __popcll(b);     // wave-uniform
    }
    if (lane == 0) scnt[wid] = (base < SEGCAP) ? base : SEGCAP;
    __syncthreads();

    const int c0 = scnt[0], c1 = scnt[1], c2 = scnt[2], c3 = scnt[3];
    const int p1 = c0, p2 = c0 + c1, p3 = c0 + c1 + c2;
    const int total = p3 + c3;

    // ---- in-LDS compaction of segments + tail pad (zi=-inf -> exact zeros) ----
    for (int j = tid; j < total + BK; j += 256) {
        if (j < total) {
            const int seg = (j >= p1) + (j >= p2) + (j >= p3);
            const int off = (seg == 0) ? 0 : (seg == 1) ? p1 : (seg == 2) ? p2 : p3;
            const int s   = (seg << 7) + (j - off);
            cxs[j] = sxs[s]; cys[j] = sys[s]; czi[j] = szi[s];
        } else {
            cxs[j] = 0.f; cys[j] = 0.f; czi[j] = -__builtin_inff();
        }
    }
    __syncthreads();

    // ---- barrier-free main loop: per-lane register fragment generation ----
    // lane (g,r) of wave (wm,wn) computes A = Wy[tm+wm+r][k0+8g..+8] (zi folded)
    //                               and B = Wx[tn+wn+r][k0+8g..+8]
    f32x4 acc = {};
    const float qy = (float)(tm + wm + r) * SCALE_S;
    const float qx = (float)(tn + wn + r) * SCALE_S;

    for (int k0 = 0; k0 < total; k0 += BK) {
        const int kb = k0 + (g << 3);

        float4 y0 = *reinterpret_cast<const float4*>(&cys[kb]);
        float4 y1 = *reinterpret_cast<const float4*>(&cys[kb + 4]);
        float4 z0 = *reinterpret_cast<const float4*>(&czi[kb]);
        float4 z1 = *reinterpret_cast<const float4*>(&czi[kb + 4]);

        float d;
        u32x4 au;
        d = qy - y0.x; const float a0 = __builtin_amdgcn_exp2f(fmaf(d, -d, z0.x));
        d = qy - y0.y; const float a1 = __builtin_amdgcn_exp2f(fmaf(d, -d, z0.y));
        d = qy - y0.z; const float a2 = __builtin_amdgcn_exp2f(fmaf(d, -d, z0.z));
        d = qy - y0.w; const float a3 = __builtin_amdgcn_exp2f(fmaf(d, -d, z0.w));
        d = qy - y1.x; const float a4 = __builtin_amdgcn_exp2f(fmaf(d, -d, z1.x));
        d = qy - y1.y; const float a5 = __builtin_amdgcn_exp2f(fmaf(d, -d, z1.y));
        d = qy - y1.z; const float a6 = __builtin_amdgcn_exp2f(fmaf(d, -d, z1.z));
        d = qy - y1.w; const float a7 = __builtin_amdgcn_exp2f(fmaf(d, -d, z1.w));
        au[0] = cvtpk(a0, a1); au[1] = cvtpk(a2, a3);
        au[2] = cvtpk(a4, a5); au[3] = cvtpk(a6, a7);

        float4 x0 = *reinterpret_cast<const float4*>(&cxs[kb]);
        float4 x1 = *reinterpret_cast<const float4*>(&cxs[kb + 4]);

        u32x4 bu;
        d = qx - x0.x; const float b0 = __builtin_amdgcn_exp2f(-(d * d));
        d = qx - x0.y; const float b1 = __builtin_amdgcn_exp2f(-(d * d));
        d = qx - x0.z; const float b2 = __builtin_amdgcn_exp2f(-(d * d));
        d = qx - x0.w; const float b3 = __builtin_amdgcn_exp2f(-(d * d));
        d = qx - x1.x; const float b4 = __builtin_amdgcn_exp2f(-(d * d));
        d = qx - x1.y; const float b5 = __builtin_amdgcn_exp2f(-(d * d));
        d = qx - x1.z; const float b6 = __builtin_amdgcn_exp2f(-(d * d));
        d = qx - x1.w; const float b7 = __builtin_amdgcn_exp2f(-(d * d));
        bu[0] = cvtpk(b0, b1); bu[1] = cvtpk(b2, b3);
        bu[2] = cvtpk(b4, b5); bu[3] = cvtpk(b6, b7);

        acc = __builtin_amdgcn_mfma_f32_16x16x32_bf16(
            __builtin_bit_cast(bf16x8, au), __builtin_bit_cast(bf16x8, bu),
            acc, 0, 0, 0);
    }

    // ---- epilogue: C/D layout col=lane&15, row=4*(lane>>4)+reg ----
    float* obase = out + (size_t)bk * (HH * WW);
    const int col  = tn + wn + r;
    const int row0 = tm + wm + (g << 2);
    #pragma unroll
    for (int j = 0; j < 4; ++j)
        obase[(size_t)(row0 + j) * WW + col] = acc[j];
}

extern "C" void kernel_launch(void* const* d_in, const int* in_sizes, int n_in,
                              void* d_out, int out_size, void* d_ws, size_t ws_size,
                              hipStream_t stream) {
    const float* p2d = (const float*)d_in[0];
    const float* pz  = (const float*)d_in[1];
    float* out       = (float*)d_out;
    const int nbk    = in_sizes[1] / NPTS;   // B*K = 32
    dim3 grid(WW / BN, HH / BM, nbk);        // (8, 8, 32) = 2048 WGs
    dim3 block(256);
    hipLaunchKernelGGL(soft_raster_kernel, grid, block, 0, stream, p2d, pz, out);
}

// Round 8
// 18.146 us; speedup vs baseline: 1.0422x; 1.0422x over previous
//
#include <hip/hip_runtime.h>
#include <hip/hip_bf16.h>

typedef __attribute__((ext_vector_type(8))) short bf16x8;   // MFMA A/B frag (8 bf16)
typedef __attribute__((ext_vector_type(4))) float f32x4;    // MFMA C/D frag
typedef __attribute__((ext_vector_type(4))) unsigned int u32x4;

constexpr int BM = 32;      // output rows (h) per block
constexpr int BN = 32;      // output cols (w) per block
constexpr int BK = 32;      // points per K-step
constexpr int NPTS = 4096;
constexpr int HH = 256;
constexpr int WW = 256;
constexpr int SEGCAP = 128;             // per-wave staging capacity (mean ~40)
constexpr int CCAP = 4 * SEGCAP + BK;   // compacted + tail pad

// S = sqrt(INV_VAR * log2(e)); exp(-INV_VAR*d^2) = exp2(-(S*d)^2)
#define SCALE_S 0.56621453f
// cutoff: dropped-point contribution <= 1e5*2^-32 = 2.3e-5 each
#define DCUT 10.0f

// HW packed f32->bf16 (RNE), D.lo = bf16(lo), D.hi = bf16(hi)
__device__ inline unsigned cvtpk(float lo, float hi) {
    unsigned r;
    asm("v_cvt_pk_bf16_f32 %0, %1, %2" : "=v"(r) : "v"(lo), "v"(hi));
    return r;
}

// 4 waves/block, each wave owns one 16x16 output quadrant.
// 2048 blocks; launch_bounds(256,4) -> VGPR budget 128 (no spills).
__global__ __launch_bounds__(256, 4) void soft_raster_kernel(
    const float* __restrict__ p2d,   // (32, 4096, 2)
    const float* __restrict__ pz,    // (32, 4096)
    float* __restrict__ out)         // (32, 256, 256)
{
    const int bk  = blockIdx.z;
    const int tm  = blockIdx.y * BM;
    const int tn  = blockIdx.x * BN;
    const int tid = threadIdx.x;

    __shared__ float sxs[4 * SEGCAP], sys[4 * SEGCAP], szi[4 * SEGCAP];
    __shared__ __align__(16) float cxs[CCAP], cys[CCAP], czi[CCAP];
    __shared__ int scnt[4];

    const int wid  = tid >> 6;          // wave 0..3 -> 2x2 quadrants
    const int lane = tid & 63;
    const int wm   = (wid >> 1) << 4;   // wave row offset (0/16)
    const int wn   = (wid & 1) << 4;    // wave col offset (0/16)
    const int g    = lane >> 4;         // k-group 0..3
    const int r    = lane & 15;

    const size_t pbase = (size_t)bk * NPTS;
    const float4* __restrict__ pxy4 =
        reinterpret_cast<const float4*>(p2d + 2 * pbase);   // 2 points / float4
    const float2* __restrict__ pz2 =
        reinterpret_cast<const float2*>(pz + pbase);        // 2 z / float2

    const float xlo = (float)tn - DCUT, xhi = (float)(tn + BN - 1) + DCUT;
    const float ylo = (float)tm - DCUT, yhi = (float)(tm + BM - 1) + DCUT;

    // ---- single-pass scan, 2 points per lane per iteration ----
    // wave w owns k in [w*1024, (w+1)*1024); 8 iterations x 128 points.
    const unsigned long long maskl = (1ull << lane) - 1ull;
    int base = 0;
    #pragma unroll 4
    for (int it = 0; it < 8; ++it) {
        const int j4 = (wid << 9) + (it << 6) + lane;   // float4 index
        float4 p = pxy4[j4];                            // x0 y0 x1 y1
        bool in0 = (p.x > xlo) && (p.x < xhi) && (p.y > ylo) && (p.y < yhi);
        bool in1 = (p.z > xlo) && (p.z < xhi) && (p.w > ylo) && (p.w < yhi);
        unsigned long long be = __ballot(in0);
        unsigned long long bo = __ballot(in1);
        if (in0 | in1) {
            float2 zz = pz2[j4];
            int pos0 = base + __popcll(be & maskl) + __popcll(bo & maskl);
            int pos1 = pos0 + (in0 ? 1 : 0);
            if (in0 && pos0 < SEGCAP) {
                const int s = (wid << 7) + pos0;
                sxs[s] = p.x * SCALE_S;
                sys[s] = p.y * SCALE_S;
                szi[s] = -__builtin_amdgcn_logf(fmaxf(zz.x, 1e-5f));
            }
            if (in1 && pos1 < SEGCAP) {
                const int s = (wid << 7) + pos1;
                sxs[s] = p.z * SCALE_S;
                sys[s] = p.w * SCALE_S;
                szi[s] = -__builtin_amdgcn_logf(fmaxf(zz.y, 1e-5f));
            }
        }
        base += __popcll(be) + __popcll(bo);    // wave-uniform
    }
    if (lane == 0) scnt[wid] = (base < SEGCAP) ? base : SEGCAP;
    __syncthreads();

    const int c0 = scnt[0], c1 = scnt[1], c2 = scnt[2], c3 = scnt[3];
    const int p1 = c0, p2 = c0 + c1, p3 = c0 + c1 + c2;
    const int total = p3 + c3;

    // ---- in-LDS compaction of segments + tail pad (zi=-inf -> exact zeros) ----
    for (int j = tid; j < total + BK; j += 256) {
        if (j < total) {
            const int seg = (j >= p1) + (j >= p2) + (j >= p3);
            const int off = (seg == 0) ? 0 : (seg == 1) ? p1 : (seg == 2) ? p2 : p3;
            const int s   = (seg << 7) + (j - off);
            cxs[j] = sxs[s]; cys[j] = sys[s]; czi[j] = szi[s];
        } else {
            cxs[j] = 0.f; cys[j] = 0.f; czi[j] = -__builtin_inff();
        }
    }
    __syncthreads();

    // ---- barrier-free main loop: per-lane register fragment generation ----
    // lane (g,r) of wave (wm,wn) computes A = Wy[tm+wm+r][k0+8g..+8] (zi folded)
    //                               and B = Wx[tn+wn+r][k0+8g..+8]
    f32x4 acc = {};
    const float qy = (float)(tm + wm + r) * SCALE_S;
    const float qx = (float)(tn + wn + r) * SCALE_S;

    for (int k0 = 0; k0 < total; k0 += BK) {
        const int kb = k0 + (g << 3);

        float4 y0 = *reinterpret_cast<const float4*>(&cys[kb]);
        float4 y1 = *reinterpret_cast<const float4*>(&cys[kb + 4]);
        float4 z0 = *reinterpret_cast<const float4*>(&czi[kb]);
        float4 z1 = *reinterpret_cast<const float4*>(&czi[kb + 4]);

        float d;
        u32x4 au;
        d = qy - y0.x; const float a0 = __builtin_amdgcn_exp2f(fmaf(d, -d, z0.x));
        d = qy - y0.y; const float a1 = __builtin_amdgcn_exp2f(fmaf(d, -d, z0.y));
        d = qy - y0.z; const float a2 = __builtin_amdgcn_exp2f(fmaf(d, -d, z0.z));
        d = qy - y0.w; const float a3 = __builtin_amdgcn_exp2f(fmaf(d, -d, z0.w));
        d = qy - y1.x; const float a4 = __builtin_amdgcn_exp2f(fmaf(d, -d, z1.x));
        d = qy - y1.y; const float a5 = __builtin_amdgcn_exp2f(fmaf(d, -d, z1.y));
        d = qy - y1.z; const float a6 = __builtin_amdgcn_exp2f(fmaf(d, -d, z1.z));
        d = qy - y1.w; const float a7 = __builtin_amdgcn_exp2f(fmaf(d, -d, z1.w));
        au[0] = cvtpk(a0, a1); au[1] = cvtpk(a2, a3);
        au[2] = cvtpk(a4, a5); au[3] = cvtpk(a6, a7);

        float4 x0 = *reinterpret_cast<const float4*>(&cxs[kb]);
        float4 x1 = *reinterpret_cast<const float4*>(&cxs[kb + 4]);

        u32x4 bu;
        d = qx - x0.x; const float b0 = __builtin_amdgcn_exp2f(-(d * d));
        d = qx - x0.y; const float b1 = __builtin_amdgcn_exp2f(-(d * d));
        d = qx - x0.z; const float b2 = __builtin_amdgcn_exp2f(-(d * d));
        d = qx - x0.w; const float b3 = __builtin_amdgcn_exp2f(-(d * d));
        d = qx - x1.x; const float b4 = __builtin_amdgcn_exp2f(-(d * d));
        d = qx - x1.y; const float b5 = __builtin_amdgcn_exp2f(-(d * d));
        d = qx - x1.z; const float b6 = __builtin_amdgcn_exp2f(-(d * d));
        d = qx - x1.w; const float b7 = __builtin_amdgcn_exp2f(-(d * d));
        bu[0] = cvtpk(b0, b1); bu[1] = cvtpk(b2, b3);
        bu[2] = cvtpk(b4, b5); bu[3] = cvtpk(b6, b7);

        acc = __builtin_amdgcn_mfma_f32_16x16x32_bf16(
            __builtin_bit_cast(bf16x8, au), __builtin_bit_cast(bf16x8, bu),
            acc, 0, 0, 0);
    }

    // ---- epilogue: C/D layout col=lane&15, row=4*(lane>>4)+reg ----
    float* obase = out + (size_t)bk * (HH * WW);
    const int col  = tn + wn + r;
    const int row0 = tm + wm + (g << 2);
    #pragma unroll
    for (int j = 0; j < 4; ++j)
        obase[(size_t)(row0 + j) * WW + col] = acc[j];
}

extern "C" void kernel_launch(void* const* d_in, const int* in_sizes, int n_in,
                              void* d_out, int out_size, void* d_ws, size_t ws_size,
                              hipStream_t stream) {
    const float* p2d = (const float*)d_in[0];
    const float* pz  = (const float*)d_in[1];
    float* out       = (float*)d_out;
    const int nbk    = in_sizes[1] / NPTS;   // B*K = 32
    dim3 grid(WW / BN, HH / BM, nbk);        // (8, 8, 32) = 2048 WGs
    dim3 block(256);
    hipLaunchKernelGGL(soft_raster_kernel, grid, block, 0, stream, p2d, pz, out);
}

// Round 9
// 15.982 us; speedup vs baseline: 1.1834x; 1.1355x over previous
//
#include <hip/hip_runtime.h>
#include <hip/hip_bf16.h>

typedef __attribute__((ext_vector_type(8))) short bf16x8;   // MFMA A/B frag (8 bf16)
typedef __attribute__((ext_vector_type(4))) float f32x4;    // MFMA C/D frag
typedef __attribute__((ext_vector_type(4))) unsigned int u32x4;

constexpr int NPTS = 4096;
constexpr int HH = 256;
constexpr int WW = 256;
constexpr int PSEG = 192;    // primary per-wave segment cap (mean ~104, +9 sigma)
constexpr int CCAPW = 288;   // per-wave compact region (cap 256 + pad to 32)

// S = sqrt(INV_VAR * log2(e)); exp(-INV_VAR*d^2) = exp2(-(S*d)^2)
#define SCALE_S 0.56621453f
// cutoff: dropped-point contribution <= 1e5*2^-32 = 2.3e-5 each
#define DCUT 10.0f

// HW packed f32->bf16 (RNE), D.lo = bf16(lo), D.hi = bf16(hi)
__device__ inline unsigned cvtpk(float lo, float hi) {
    unsigned r;
    asm("v_cvt_pk_bf16_f32 %0, %1, %2" : "=v"(r) : "v"(lo), "v"(hi));
    return r;
}

// Block = 4 waves covering a 64x64 region; each WAVE owns one full 32x32 tile
// (zero duplicated generation). Grid 512; one barrier per block.
__global__ __launch_bounds__(256, 2) void soft_raster_kernel(
    const float* __restrict__ p2d,   // (32, 4096, 2)
    const float* __restrict__ pz,    // (32, 4096)
    float* __restrict__ out)         // (32, 256, 256)
{
    const int bk  = blockIdx.z;
    const int tm  = blockIdx.y * 64;
    const int tn  = blockIdx.x * 64;
    const int tid = threadIdx.x;

    __shared__ float sxs[4 * PSEG], sys[4 * PSEG], szi[4 * PSEG];   // primary
    __shared__ __align__(16) float cxs[4 * CCAPW], cys[4 * CCAPW], czi[4 * CCAPW];
    __shared__ int scnt[4];

    const int wid  = tid >> 6;
    const int lane = tid & 63;
    const int tmw  = tm + ((wid >> 1) << 5);   // this wave's 32x32 tile
    const int tnw  = tn + ((wid & 1) << 5);
    const int g    = lane >> 4;                // k-group 0..3
    const int r    = lane & 15;

    const size_t pbase = (size_t)bk * NPTS;
    const float4* __restrict__ pxy4 =
        reinterpret_cast<const float4*>(p2d + 2 * pbase);   // 2 points / float4
    const float2* __restrict__ pz2 =
        reinterpret_cast<const float2*>(pz + pbase);

    // ---- primary scan: block window (64x64 + apron), per-wave segments ----
    const float Xlo = (float)tn - DCUT, Xhi = (float)(tn + 63) + DCUT;
    const float Ylo = (float)tm - DCUT, Yhi = (float)(tm + 63) + DCUT;
    const unsigned long long maskl = (1ull << lane) - 1ull;

    int base = 0;
    #pragma unroll 4
    for (int it = 0; it < 8; ++it) {
        const int j4 = (wid << 9) + (it << 6) + lane;   // wave owns 1024 points
        float4 p = pxy4[j4];                            // x0 y0 x1 y1
        bool in0 = (p.x > Xlo) && (p.x < Xhi) && (p.y > Ylo) && (p.y < Yhi);
        bool in1 = (p.z > Xlo) && (p.z < Xhi) && (p.w > Ylo) && (p.w < Yhi);
        unsigned long long be = __ballot(in0);
        unsigned long long bo = __ballot(in1);
        if (in0 | in1) {
            float2 zz = pz2[j4];
            int pos0 = base + __popcll(be & maskl) + __popcll(bo & maskl);
            int pos1 = pos0 + (in0 ? 1 : 0);
            if (in0 && pos0 < PSEG) {
                const int s = wid * PSEG + pos0;
                sxs[s] = p.x * SCALE_S;
                sys[s] = p.y * SCALE_S;
                szi[s] = -__builtin_amdgcn_logf(fmaxf(zz.x, 1e-5f));
            }
            if (in1 && pos1 < PSEG) {
                const int s = wid * PSEG + pos1;
                sxs[s] = p.z * SCALE_S;
                sys[s] = p.w * SCALE_S;
                szi[s] = -__builtin_amdgcn_logf(fmaxf(zz.y, 1e-5f));
            }
        }
        base += __popcll(be) + __popcll(bo);
    }
    if (lane == 0) scnt[wid] = (base < PSEG) ? base : PSEG;
    __syncthreads();   // the only block barrier

    // ---- secondary in-LDS filter: this wave's 32x32 window ----
    const float xlo = ((float)tnw - DCUT) * SCALE_S;
    const float xhi = ((float)(tnw + 31) + DCUT) * SCALE_S;
    const float ylo = ((float)tmw - DCUT) * SCALE_S;
    const float yhi = ((float)(tmw + 31) + DCUT) * SCALE_S;
    float* __restrict__ wxs = cxs + wid * CCAPW;
    float* __restrict__ wys = cys + wid * CCAPW;
    float* __restrict__ wzi = czi + wid * CCAPW;

    int cw = 0;
    #pragma unroll
    for (int s = 0; s < 4; ++s) {
        const int cs = scnt[s];
        for (int j0 = 0; j0 < cs; j0 += 64) {
            const int j = j0 + lane;
            bool in = false;
            float xs = 0.f, ys = 0.f;
            if (j < cs) {
                xs = sxs[s * PSEG + j];
                ys = sys[s * PSEG + j];
                in = (xs > xlo) && (xs < xhi) && (ys > ylo) && (ys < yhi);
            }
            unsigned long long b = __ballot(in);
            int pos = cw + __popcll(b & maskl);
            if (in && pos < 256) {
                wxs[pos] = xs;
                wys[pos] = ys;
                wzi[pos] = szi[s * PSEG + j];
            }
            cw += __popcll(b);
        }
    }
    cw = (cw < 256) ? cw : 256;
    const int pw = (cw + 31) & ~31;          // pad to K-step multiple
    for (int j = cw + lane; j < pw; j += 64) {
        wxs[j] = 0.f; wys[j] = 0.f; wzi[j] = -__builtin_inff();   // exact zeros
    }

    // ---- barrier-free main loop: wave-private, register-direct, 4 MFMA/step ----
    f32x4 acc[2][2] = {};
    const float qy0 = (float)(tmw + r)      * SCALE_S;
    const float qy1 = (float)(tmw + 16 + r) * SCALE_S;
    const float qx0 = (float)(tnw + r)      * SCALE_S;
    const float qx1 = (float)(tnw + 16 + r) * SCALE_S;

    for (int k0 = 0; k0 < pw; k0 += 32) {
        const int kb = k0 + (g << 3);

        float4 y0 = *reinterpret_cast<const float4*>(&wys[kb]);
        float4 y1 = *reinterpret_cast<const float4*>(&wys[kb + 4]);
        float4 z0 = *reinterpret_cast<const float4*>(&wzi[kb]);
        float4 z1 = *reinterpret_cast<const float4*>(&wzi[kb + 4]);
        float4 x0 = *reinterpret_cast<const float4*>(&wxs[kb]);
        float4 x1 = *reinterpret_cast<const float4*>(&wxs[kb + 4]);

        u32x4 au[2], bu[2];
        #pragma unroll
        for (int mi = 0; mi < 2; ++mi) {
            const float qy = mi ? qy1 : qy0;
            float d;
            d = qy - y0.x; const float a0 = __builtin_amdgcn_exp2f(fmaf(d, -d, z0.x));
            d = qy - y0.y; const float a1 = __builtin_amdgcn_exp2f(fmaf(d, -d, z0.y));
            d = qy - y0.z; const float a2 = __builtin_amdgcn_exp2f(fmaf(d, -d, z0.z));
            d = qy - y0.w; const float a3 = __builtin_amdgcn_exp2f(fmaf(d, -d, z0.w));
            d = qy - y1.x; const float a4 = __builtin_amdgcn_exp2f(fmaf(d, -d, z1.x));
            d = qy - y1.y; const float a5 = __builtin_amdgcn_exp2f(fmaf(d, -d, z1.y));
            d = qy - y1.z; const float a6 = __builtin_amdgcn_exp2f(fmaf(d, -d, z1.z));
            d = qy - y1.w; const float a7 = __builtin_amdgcn_exp2f(fmaf(d, -d, z1.w));
            au[mi][0] = cvtpk(a0, a1); au[mi][1] = cvtpk(a2, a3);
            au[mi][2] = cvtpk(a4, a5); au[mi][3] = cvtpk(a6, a7);
        }
        #pragma unroll
        for (int ni = 0; ni < 2; ++ni) {
            const float qx = ni ? qx1 : qx0;
            float d;
            d = qx - x0.x; const float b0 = __builtin_amdgcn_exp2f(-(d * d));
            d = qx - x0.y; const float b1 = __builtin_amdgcn_exp2f(-(d * d));
            d = qx - x0.z; const float b2 = __builtin_amdgcn_exp2f(-(d * d));
            d = qx - x0.w; const float b3 = __builtin_amdgcn_exp2f(-(d * d));
            d = qx - x1.x; const float b4 = __builtin_amdgcn_exp2f(-(d * d));
            d = qx - x1.y; const float b5 = __builtin_amdgcn_exp2f(-(d * d));
            d = qx - x1.z; const float b6 = __builtin_amdgcn_exp2f(-(d * d));
            d = qx - x1.w; const float b7 = __builtin_amdgcn_exp2f(-(d * d));
            bu[ni][0] = cvtpk(b0, b1); bu[ni][1] = cvtpk(b2, b3);
            bu[ni][2] = cvtpk(b4, b5); bu[ni][3] = cvtpk(b6, b7);
        }
        #pragma unroll
        for (int mi = 0; mi < 2; ++mi)
            #pragma unroll
            for (int ni = 0; ni < 2; ++ni)
                acc[mi][ni] = __builtin_amdgcn_mfma_f32_16x16x32_bf16(
                    __builtin_bit_cast(bf16x8, au[mi]),
                    __builtin_bit_cast(bf16x8, bu[ni]), acc[mi][ni], 0, 0, 0);
    }

    // ---- epilogue: C/D layout col=lane&15, row=4*(lane>>4)+reg ----
    float* obase = out + (size_t)bk * (HH * WW);
    #pragma unroll
    for (int mi = 0; mi < 2; ++mi) {
        #pragma unroll
        for (int ni = 0; ni < 2; ++ni) {
            const int col  = tnw + (ni << 4) + r;
            const int row0 = tmw + (mi << 4) + (g << 2);
            #pragma unroll
            for (int j = 0; j < 4; ++j)
                obase[(size_t)(row0 + j) * WW + col] = acc[mi][ni][j];
        }
    }
}

extern "C" void kernel_launch(void* const* d_in, const int* in_sizes, int n_in,
                              void* d_out, int out_size, void* d_ws, size_t ws_size,
                              hipStream_t stream) {
    const float* p2d = (const float*)d_in[0];
    const float* pz  = (const float*)d_in[1];
    float* out       = (float*)d_out;
    const int nbk    = in_sizes[1] / NPTS;   // B*K = 32
    dim3 grid(WW / 64, HH / 64, nbk);        // (4, 4, 32) = 512 WGs
    dim3 block(256);
    hipLaunchKernelGGL(soft_raster_kernel, grid, block, 0, stream, p2d, pz, out);
}

// Round 10
// 15.067 us; speedup vs baseline: 1.2552x; 1.0607x over previous
//
#include <hip/hip_runtime.h>
#include <hip/hip_bf16.h>

typedef __attribute__((ext_vector_type(8))) short bf16x8;   // MFMA A/B frag (8 bf16)
typedef __attribute__((ext_vector_type(4))) float f32x4;    // MFMA C/D frag
typedef __attribute__((ext_vector_type(4))) unsigned int u32x4;

constexpr int NPTS = 4096;
constexpr int HH = 256;
constexpr int WW = 256;
constexpr int PSEG = 256;    // primary per-wave segment cap (mean ~104; also 4*lane+3 < 256)
constexpr int CCAPW = 288;   // per-wave compact region (cap 256 + pad to 32)

// S = sqrt(INV_VAR * log2(e)); exp(-INV_VAR*d^2) = exp2(-(S*d)^2)
#define SCALE_S 0.56621453f
// cutoff: dropped-point contribution <= 1e5*2^-32 = 2.3e-5 each
#define DCUT 10.0f

// HW packed f32->bf16 (RNE), D.lo = bf16(lo), D.hi = bf16(hi)
__device__ inline unsigned cvtpk(float lo, float hi) {
    unsigned r;
    asm("v_cvt_pk_bf16_f32 %0, %1, %2" : "=v"(r) : "v"(lo), "v"(hi));
    return r;
}

// Block = 4 waves covering 64x64; each WAVE owns one 32x32 tile.
// Grid 512; one barrier per block; latency-optimized scan + filter.
__global__ __launch_bounds__(256, 2) void soft_raster_kernel(
    const float* __restrict__ p2d,   // (32, 4096, 2)
    const float* __restrict__ pz,    // (32, 4096)
    float* __restrict__ out)         // (32, 256, 256)
{
    const int bk  = blockIdx.z;
    const int tm  = blockIdx.y * 64;
    const int tn  = blockIdx.x * 64;
    const int tid = threadIdx.x;

    __shared__ __align__(16) float sxs[4 * PSEG], sys[4 * PSEG], szi[4 * PSEG];
    __shared__ __align__(16) float cxs[4 * CCAPW], cys[4 * CCAPW], czi[4 * CCAPW];
    __shared__ int scnt[4];

    const int wid  = tid >> 6;
    const int lane = tid & 63;
    const int tmw  = tm + ((wid >> 1) << 5);   // this wave's 32x32 tile
    const int tnw  = tn + ((wid & 1) << 5);
    const int g    = lane >> 4;                // k-group 0..3
    const int r    = lane & 15;

    const size_t pbase = (size_t)bk * NPTS;
    const float4* __restrict__ pxy4 =
        reinterpret_cast<const float4*>(p2d + 2 * pbase);   // 2 points / float4
    const float2* __restrict__ pz2 =
        reinterpret_cast<const float2*>(pz + pbase);

    // ---- primary scan: prefetch ALL loads, then ballot chain ----
    const float Xlo = (float)tn - DCUT, Xhi = (float)(tn + 63) + DCUT;
    const float Ylo = (float)tm - DCUT, Yhi = (float)(tm + 63) + DCUT;
    const unsigned long long maskl = (1ull << lane) - 1ull;

    float4 P[8];
    float2 Z[8];
    #pragma unroll
    for (int it = 0; it < 8; ++it) P[it] = pxy4[(wid << 9) + (it << 6) + lane];
    #pragma unroll
    for (int it = 0; it < 8; ++it) Z[it] = pz2[(wid << 9) + (it << 6) + lane];

    int base = 0;
    #pragma unroll
    for (int it = 0; it < 8; ++it) {
        const float4 p  = P[it];                        // x0 y0 x1 y1
        const float2 zz = Z[it];
        bool in0 = (p.x > Xlo) && (p.x < Xhi) && (p.y > Ylo) && (p.y < Yhi);
        bool in1 = (p.z > Xlo) && (p.z < Xhi) && (p.w > Ylo) && (p.w < Yhi);
        unsigned long long be = __ballot(in0);
        unsigned long long bo = __ballot(in1);
        int pos0 = base + __popcll(be & maskl) + __popcll(bo & maskl);
        int pos1 = pos0 + (in0 ? 1 : 0);
        if (in0 && pos0 < PSEG) {
            const int s = (wid << 8) + pos0;
            sxs[s] = p.x * SCALE_S;
            sys[s] = p.y * SCALE_S;
            szi[s] = -__builtin_amdgcn_logf(fmaxf(zz.x, 1e-5f));
        }
        if (in1 && pos1 < PSEG) {
            const int s = (wid << 8) + pos1;
            sxs[s] = p.z * SCALE_S;
            sys[s] = p.w * SCALE_S;
            szi[s] = -__builtin_amdgcn_logf(fmaxf(zz.y, 1e-5f));
        }
        base += __popcll(be) + __popcll(bo);
    }
    if (lane == 0) scnt[wid] = (base < PSEG) ? base : PSEG;
    __syncthreads();   // the only block barrier

    // ---- secondary filter: 4 points/lane, ONE iteration per segment ----
    const float xlo = ((float)tnw - DCUT) * SCALE_S;
    const float xhi = ((float)(tnw + 31) + DCUT) * SCALE_S;
    const float ylo = ((float)tmw - DCUT) * SCALE_S;
    const float yhi = ((float)(tmw + 31) + DCUT) * SCALE_S;
    float* __restrict__ wxs = cxs + wid * CCAPW;
    float* __restrict__ wys = cys + wid * CCAPW;
    float* __restrict__ wzi = czi + wid * CCAPW;

    int cw = 0;
    #pragma unroll
    for (int s = 0; s < 4; ++s) {
        const int cs = scnt[s];
        const int jb = lane << 2;     // this lane's 4 candidate slots
        const float4 x4 = *reinterpret_cast<const float4*>(&sxs[(s << 8) + jb]);
        const float4 y4 = *reinterpret_cast<const float4*>(&sys[(s << 8) + jb]);
        const float4 z4 = *reinterpret_cast<const float4*>(&szi[(s << 8) + jb]);
        bool i0 = (jb + 0 < cs) && (x4.x > xlo) && (x4.x < xhi) && (y4.x > ylo) && (y4.x < yhi);
        bool i1 = (jb + 1 < cs) && (x4.y > xlo) && (x4.y < xhi) && (y4.y > ylo) && (y4.y < yhi);
        bool i2 = (jb + 2 < cs) && (x4.z > xlo) && (x4.z < xhi) && (y4.z > ylo) && (y4.z < yhi);
        bool i3 = (jb + 3 < cs) && (x4.w > xlo) && (x4.w < xhi) && (y4.w > ylo) && (y4.w < yhi);
        unsigned long long b0 = __ballot(i0), b1 = __ballot(i1);
        unsigned long long b2 = __ballot(i2), b3 = __ballot(i3);
        const int c0 = __popcll(b0), c1 = __popcll(b1), c2 = __popcll(b2);
        int pos0 = cw + __popcll(b0 & maskl);
        int pos1 = cw + c0 + __popcll(b1 & maskl);
        int pos2 = cw + c0 + c1 + __popcll(b2 & maskl);
        int pos3 = cw + c0 + c1 + c2 + __popcll(b3 & maskl);
        if (i0 && pos0 < 256) { wxs[pos0] = x4.x; wys[pos0] = y4.x; wzi[pos0] = z4.x; }
        if (i1 && pos1 < 256) { wxs[pos1] = x4.y; wys[pos1] = y4.y; wzi[pos1] = z4.y; }
        if (i2 && pos2 < 256) { wxs[pos2] = x4.z; wys[pos2] = y4.z; wzi[pos2] = z4.z; }
        if (i3 && pos3 < 256) { wxs[pos3] = x4.w; wys[pos3] = y4.w; wzi[pos3] = z4.w; }
        cw += c0 + c1 + c2 + __popcll(b3);
    }
    cw = (cw < 256) ? cw : 256;
    const int pw = (cw + 31) & ~31;          // pad to K-step multiple
    for (int j = cw + lane; j < pw; j += 64) {
        wxs[j] = 0.f; wys[j] = 0.f; wzi[j] = -__builtin_inff();   // exact zeros
    }

    // ---- barrier-free main loop: wave-private, register-direct, 4 MFMA/step ----
    f32x4 acc[2][2] = {};
    const float qy0 = (float)(tmw + r)      * SCALE_S;
    const float qy1 = (float)(tmw + 16 + r) * SCALE_S;
    const float qx0 = (float)(tnw + r)      * SCALE_S;
    const float qx1 = (float)(tnw + 16 + r) * SCALE_S;

    for (int k0 = 0; k0 < pw; k0 += 32) {
        const int kb = k0 + (g << 3);

        float4 y0 = *reinterpret_cast<const float4*>(&wys[kb]);
        float4 y1 = *reinterpret_cast<const float4*>(&wys[kb + 4]);
        float4 z0 = *reinterpret_cast<const float4*>(&wzi[kb]);
        float4 z1 = *reinterpret_cast<const float4*>(&wzi[kb + 4]);
        float4 x0 = *reinterpret_cast<const float4*>(&wxs[kb]);
        float4 x1 = *reinterpret_cast<const float4*>(&wxs[kb + 4]);

        u32x4 au[2], bu[2];
        #pragma unroll
        for (int mi = 0; mi < 2; ++mi) {
            const float qy = mi ? qy1 : qy0;
            float d;
            d = qy - y0.x; const float a0 = __builtin_amdgcn_exp2f(fmaf(d, -d, z0.x));
            d = qy - y0.y; const float a1 = __builtin_amdgcn_exp2f(fmaf(d, -d, z0.y));
            d = qy - y0.z; const float a2 = __builtin_amdgcn_exp2f(fmaf(d, -d, z0.z));
            d = qy - y0.w; const float a3 = __builtin_amdgcn_exp2f(fmaf(d, -d, z0.w));
            d = qy - y1.x; const float a4 = __builtin_amdgcn_exp2f(fmaf(d, -d, z1.x));
            d = qy - y1.y; const float a5 = __builtin_amdgcn_exp2f(fmaf(d, -d, z1.y));
            d = qy - y1.z; const float a6 = __builtin_amdgcn_exp2f(fmaf(d, -d, z1.z));
            d = qy - y1.w; const float a7 = __builtin_amdgcn_exp2f(fmaf(d, -d, z1.w));
            au[mi][0] = cvtpk(a0, a1); au[mi][1] = cvtpk(a2, a3);
            au[mi][2] = cvtpk(a4, a5); au[mi][3] = cvtpk(a6, a7);
        }
        #pragma unroll
        for (int ni = 0; ni < 2; ++ni) {
            const float qx = ni ? qx1 : qx0;
            float d;
            d = qx - x0.x; const float b0 = __builtin_amdgcn_exp2f(-(d * d));
            d = qx - x0.y; const float b1 = __builtin_amdgcn_exp2f(-(d * d));
            d = qx - x0.z; const float b2 = __builtin_amdgcn_exp2f(-(d * d));
            d = qx - x0.w; const float b3 = __builtin_amdgcn_exp2f(-(d * d));
            d = qx - x1.x; const float b4 = __builtin_amdgcn_exp2f(-(d * d));
            d = qx - x1.y; const float b5 = __builtin_amdgcn_exp2f(-(d * d));
            d = qx - x1.z; const float b6 = __builtin_amdgcn_exp2f(-(d * d));
            d = qx - x1.w; const float b7 = __builtin_amdgcn_exp2f(-(d * d));
            bu[ni][0] = cvtpk(b0, b1); bu[ni][1] = cvtpk(b2, b3);
            bu[ni][2] = cvtpk(b4, b5); bu[ni][3] = cvtpk(b6, b7);
        }
        #pragma unroll
        for (int mi = 0; mi < 2; ++mi)
            #pragma unroll
            for (int ni = 0; ni < 2; ++ni)
                acc[mi][ni] = __builtin_amdgcn_mfma_f32_16x16x32_bf16(
                    __builtin_bit_cast(bf16x8, au[mi]),
                    __builtin_bit_cast(bf16x8, bu[ni]), acc[mi][ni], 0, 0, 0);
    }

    // ---- epilogue: C/D layout col=lane&15, row=4*(lane>>4)+reg ----
    float* obase = out + (size_t)bk * (HH * WW);
    #pragma unroll
    for (int mi = 0; mi < 2; ++mi) {
        #pragma unroll
        for (int ni = 0; ni < 2; ++ni) {
            const int col  = tnw + (ni << 4) + r;
            const int row0 = tmw + (mi << 4) + (g << 2);
            #pragma unroll
            for (int j = 0; j < 4; ++j)
                obase[(size_t)(row0 + j) * WW + col] = acc[mi][ni][j];
        }
    }
}

extern "C" void kernel_launch(void* const* d_in, const int* in_sizes, int n_in,
                              void* d_out, int out_size, void* d_ws, size_t ws_size,
                              hipStream_t stream) {
    const float* p2d = (const float*)d_in[0];
    const float* pz  = (const float*)d_in[1];
    float* out       = (float*)d_out;
    const int nbk    = in_sizes[1] / NPTS;   // B*K = 32
    dim3 grid(WW / 64, HH / 64, nbk);        // (4, 4, 32) = 512 WGs
    dim3 block(256);
    hipLaunchKernelGGL(soft_raster_kernel, grid, block, 0, stream, p2d, pz, out);
}